// Round 23
// baseline (415.593 us; speedup 1.0000x reference)
//
#include <hip/hip_runtime.h>
#include <hip/hip_bf16.h>

#define HID 64
#define RPW 16
#define KCH 8

typedef __hip_bfloat16  bf16;
typedef __hip_bfloat162 bf162;
typedef __attribute__((ext_vector_type(8))) short bf8v;
typedef __attribute__((ext_vector_type(4))) float f4v;
__device__ __forceinline__ float bl(bf16 h) { return __bfloat162float(h); }

// -------- FUSED level-1 GNN (R22, unchanged): one block per graph, 3 layers in LDS.
__global__ __launch_bounds__(256)
void level1_k(const float* __restrict__ x,
              const int* __restrict__ rs1, const int* __restrict__ csrc1,
              const float* __restrict__ W10, const float* __restrict__ W20,
              const float* __restrict__ W11, const float* __restrict__ W21,
              const float* __restrict__ W12, const float* __restrict__ W22,
              float* __restrict__ hout, int nper) {
    __shared__ float hbuf[20][64];
    __shared__ float mbuf[20][64];
    __shared__ float wl1[64 * 64];
    __shared__ float wl2[64 * 64];
    int g = blockIdx.x, t = threadIdx.x;
    int wv = t >> 6, lane = t & 63;
    int base = g * nper;
    for (int i = t; i < 20 * 32; i += 256)
        hbuf[i >> 5][i & 31] = x[(size_t)(base + (i >> 5)) * 32 + (i & 31)];
    const float* W1s[3] = {W10, W11, W12};
    const float* W2s[3] = {W20, W21, W22};
#pragma unroll 1
    for (int l = 0; l < 3; ++l) {
        int K = (l == 0) ? 32 : 64;
        const float* W1 = W1s[l];
        const float* W2 = W2s[l];
        __syncthreads();
        for (int i = t; i < K * 64; i += 256) {
            int k = i >> 6, col = i & 63;
            wl1[i] = W1[col * K + k];
            wl2[i] = W2[col * K + k];
        }
        __syncthreads();
        float accz[5], accm[5];
#pragma unroll
        for (int ri = 0; ri < 5; ++ri) {
            int r = wv + ri * 4;
            float az = 0.f, am = 0.f;
            for (int k = 0; k < K; ++k) {
                float hv = hbuf[r][k];
                az = fmaf(hv, wl1[k * 64 + lane], az);
                am = fmaf(hv, wl2[k * 64 + lane], am);
            }
            accz[ri] = az; accm[ri] = am;
        }
        __syncthreads();
#pragma unroll
        for (int ri = 0; ri < 5; ++ri)
            mbuf[wv + ri * 4][lane] = accm[ri];
        __syncthreads();
#pragma unroll
        for (int ri = 0; ri < 5; ++ri) {
            int r = wv + ri * 4;
            float acc = accz[ri];
            int s = rs1[base + r], e = rs1[base + r + 1];
            for (int k = s; k < e; ++k)
                acc += mbuf[csrc1[k] - base][lane];
            hbuf[r][lane] = fmaxf(acc, 0.f);
        }
    }
    __syncthreads();
    for (int i = t; i < 20 * 64; i += 256)
        hout[(size_t)(base + (i >> 6)) * 64 + (i & 63)] = hbuf[i >> 6][i & 63];
}

// -------- FUSED layer-0 neighsum + MFMA dual GEMM.
// Each block owns 128 rows (R divisible by 128 at both sites): gather+relu
// z-init+messages into LDS rows (bf16), sync, MFMA from LDS. Deletes the
// z-buffer round trip and one dispatch. New messages go to a FRESH buffer
// (ob != m) — cross-block gather reads of m race with writes otherwise.
// W loaded per-wave from global (fp32->bf16 inline) to keep LDS at 18KB
// (rows[128][72], 16B-aligned stride, 2-way bank alias = free per m136).
struct FJob { const bf162* zb; const bf162* m; const int* rs; const int* csrc;
              const float* Wa; const float* Wb; bf16* oa; bf16* ob;
              int R; int nb8; int nblocks; };

__device__ __forceinline__ void neigh_mfma_body(const FJob& jb, int blk, int t) {
    __shared__ bf16 rows[128][72];
    int chunk = (blk & 7) * jb.nb8 + (blk >> 3);
    int j0 = chunk * 128;
    bool active = (j0 < jb.R);
    if (active) {
        int slot = t >> 5, f2 = t & 31;
#pragma unroll 1
        for (int pass = 0; pass < 16; ++pass) {
            int jl = pass * 8 + slot;
            int j = j0 + jl;
            bf162 z0 = jb.zb[(size_t)j * 32 + f2];
            float ax = bl(z0.x), ay = bl(z0.y);
            int s = jb.rs[j], e = jb.rs[j + 1];
            const bf162* m = jb.m;
            int k = s;
            for (; k + 8 <= e; k += 8) {
                int i0 = jb.csrc[k],     i1 = jb.csrc[k + 1], i2 = jb.csrc[k + 2], i3 = jb.csrc[k + 3];
                int i4 = jb.csrc[k + 4], i5 = jb.csrc[k + 5], i6 = jb.csrc[k + 6], i7 = jb.csrc[k + 7];
                bf162 v0 = m[(size_t)i0 * 32 + f2], v1 = m[(size_t)i1 * 32 + f2];
                bf162 v2 = m[(size_t)i2 * 32 + f2], v3 = m[(size_t)i3 * 32 + f2];
                bf162 v4 = m[(size_t)i4 * 32 + f2], v5 = m[(size_t)i5 * 32 + f2];
                bf162 v6 = m[(size_t)i6 * 32 + f2], v7 = m[(size_t)i7 * 32 + f2];
                ax += ((bl(v0.x) + bl(v1.x)) + (bl(v2.x) + bl(v3.x)))
                    + ((bl(v4.x) + bl(v5.x)) + (bl(v6.x) + bl(v7.x)));
                ay += ((bl(v0.y) + bl(v1.y)) + (bl(v2.y) + bl(v3.y)))
                    + ((bl(v4.y) + bl(v5.y)) + (bl(v6.y) + bl(v7.y)));
            }
            for (; k + 4 <= e; k += 4) {
                int i0 = jb.csrc[k], i1 = jb.csrc[k + 1], i2 = jb.csrc[k + 2], i3 = jb.csrc[k + 3];
                bf162 v0 = m[(size_t)i0 * 32 + f2], v1 = m[(size_t)i1 * 32 + f2];
                bf162 v2 = m[(size_t)i2 * 32 + f2], v3 = m[(size_t)i3 * 32 + f2];
                ax += (bl(v0.x) + bl(v1.x)) + (bl(v2.x) + bl(v3.x));
                ay += (bl(v0.y) + bl(v1.y)) + (bl(v2.y) + bl(v3.y));
            }
            for (; k < e; ++k) {
                bf162 v = m[(size_t)jb.csrc[k] * 32 + f2];
                ax += bl(v.x); ay += bl(v.y);
            }
            bf162 o; o.x = __float2bfloat16(fmaxf(ax, 0.f)); o.y = __float2bfloat16(fmaxf(ay, 0.f));
            *(bf162*)&rows[jl][2 * f2] = o;
        }
    }
    __syncthreads();
    if (!active) return;
    int lane = t & 63, wv = t >> 6;
    int quad = lane >> 4, m16 = lane & 15;
    int r0l = wv * 32;
    bf8v a[2][2];
#pragma unroll
    for (int rt = 0; rt < 2; ++rt)
#pragma unroll
        for (int kt = 0; kt < 2; ++kt)
            a[rt][kt] = *(const bf8v*)&rows[r0l + rt * 16 + m16][kt * 32 + quad * 8];
#pragma unroll
    for (int n = 0; n < 4; ++n) {
        // B fragments: row n*16+m16 of W, k-range quad*8 + {0,32}; fp32 -> bf16
        bf8v b1k0, b1k1, b2k0, b2k1;
        {
            const float* wa = jb.Wa + (size_t)(n * 16 + m16) * 64 + quad * 8;
            const float* wb = jb.Wb + (size_t)(n * 16 + m16) * 64 + quad * 8;
#pragma unroll
            for (int q = 0; q < 8; ++q) {
                ((bf16*)&b1k0)[q] = __float2bfloat16(wa[q]);
                ((bf16*)&b1k1)[q] = __float2bfloat16(wa[32 + q]);
                ((bf16*)&b2k0)[q] = __float2bfloat16(wb[q]);
                ((bf16*)&b2k1)[q] = __float2bfloat16(wb[32 + q]);
            }
        }
#pragma unroll
        for (int rt = 0; rt < 2; ++rt) {
            f4v acca = {0.f, 0.f, 0.f, 0.f};
            f4v accb = {0.f, 0.f, 0.f, 0.f};
            acca = __builtin_amdgcn_mfma_f32_16x16x32_bf16(a[rt][0], b1k0, acca, 0, 0, 0);
            acca = __builtin_amdgcn_mfma_f32_16x16x32_bf16(a[rt][1], b1k1, acca, 0, 0, 0);
            accb = __builtin_amdgcn_mfma_f32_16x16x32_bf16(a[rt][0], b2k0, accb, 0, 0, 0);
            accb = __builtin_amdgcn_mfma_f32_16x16x32_bf16(a[rt][1], b2k1, accb, 0, 0, 0);
            int col = n * 16 + m16;
#pragma unroll
            for (int r = 0; r < 4; ++r) {
                int row = j0 + r0l + rt * 16 + quad * 4 + r;
                jb.oa[(size_t)row * 64 + col] = __float2bfloat16(acca[r]);
                jb.ob[(size_t)row * 64 + col] = __float2bfloat16(accb[r]);
            }
        }
    }
}

__global__ __launch_bounds__(256)
void neigh_mfma2_k(FJob j3, FJob j2) {
    if ((int)blockIdx.x < j3.nblocks) neigh_mfma_body(j3, blockIdx.x, threadIdx.x);
    else                              neigh_mfma_body(j2, blockIdx.x - j3.nblocks, threadIdx.x);
}

// -------- batched table GEMM (R22): 5 jobs, bf162 interleaved output.
struct TJob { const float* Wa; const float* Wb; bf162* o; int ldw; int coloff; };
struct TJobs5 { TJob j[5]; };

__global__ __attribute__((amdgpu_flat_work_group_size(256, 256),
                          amdgpu_waves_per_eu(6, 6)))
void gemm2_table(const float* in, TJobs5 jobs, int R, int bpj) {
    int jobi = blockIdx.x / bpj;
    int lb = blockIdx.x % bpj;
    TJob jb = jobs.j[jobi];
    int lane = threadIdx.x & 63;
    int wid = lb * 4 + (threadIdx.x >> 6);
    int j0 = __builtin_amdgcn_readfirstlane(wid * RPW);
    if (j0 >= R) return;
    float accx[RPW], accy[RPW];
#pragma unroll
    for (int r = 0; r < RPW; ++r) { accx[r] = 0.f; accy[r] = 0.f; }
    const float* pa = jb.Wa + (size_t)lane * jb.ldw + jb.coloff;
    const float* pb = jb.Wb + (size_t)lane * jb.ldw + jb.coloff;
#pragma unroll 1
    for (int kc = 0; kc < 64; kc += KCH) {
        float wx[KCH], wy[KCH];
#pragma unroll
        for (int kk = 0; kk < KCH; ++kk) { wx[kk] = pa[kc + kk]; wy[kk] = pb[kc + kk]; }
#pragma unroll
        for (int r = 0; r < RPW; ++r) {
            const float* rp = in + (size_t)(j0 + r) * 64 + kc;
#pragma unroll
            for (int kk = 0; kk < KCH; ++kk) {
                float s = rp[kk];
                accx[r] = fmaf(s, wx[kk], accx[r]);
                accy[r] = fmaf(s, wy[kk], accy[r]);
            }
        }
    }
#pragma unroll
    for (int r = 0; r < RPW; ++r) {
        int j = j0 + r;
        bf162 v; v.x = __float2bfloat16(accx[r]); v.y = __float2bfloat16(accy[r]);
        jb.o[(size_t)j * 64 + lane] = v;
    }
}

// ======== batched CSR build ========
__global__ void zero4_k(int* p1, int s1, int* p2, int s2, int* p3, int s3,
                        int* p4, int s4, int nb1, int nb2, int nb3) {
    int b = blockIdx.x; int* p; int n; int lb;
    if (b < nb1)                 { p = p1; n = s1; lb = b; }
    else if (b < nb1 + nb2)      { p = p2; n = s2; lb = b - nb1; }
    else if (b < nb1 + nb2 + nb3){ p = p3; n = s3; lb = b - nb1 - nb2; }
    else                         { p = p4; n = s4; lb = b - nb1 - nb2 - nb3; }
    int i = lb * 256 + threadIdx.x;
    if (i < n) p[i] = 0;
}

__global__ void hist3_k(const int* e1, int E1, int* c1,
                        const int* e2, int E2, int* c2,
                        const int* e3, int E3, int* c3, int nb1, int nb2) {
    int b = blockIdx.x; const int* dst; int* c; int E; int lb;
    if (b < nb1)            { dst = e1 + E1; c = c1; E = E1; lb = b; }
    else if (b < nb1 + nb2) { dst = e2 + E2; c = c2; E = E2; lb = b - nb1; }
    else                    { dst = e3 + E3; c = c3; E = E3; lb = b - nb1 - nb2; }
    int e = lb * 256 + threadIdx.x;
    if (e < E) atomicAdd(&c[dst[e]], 1);
}

__device__ __forceinline__ void scan1_body(const int* __restrict__ cnt, int* __restrict__ rs,
                                           int* __restrict__ bsum, int n1, int n, int lb) {
    __shared__ int wsum[4];
    int t = threadIdx.x;
    int base = lb * 1024 + t * 4;
    int v[4]; int s = 0;
#pragma unroll
    for (int i = 0; i < 4; ++i) { int idx = base + i; v[i] = s; s += (idx < n) ? cnt[idx] : 0; }
    int lane = t & 63, wv = t >> 6;
    int x = s;
#pragma unroll
    for (int off = 1; off < 64; off <<= 1) { int y = __shfl_up(x, off, 64); if (lane >= off) x += y; }
    if (lane == 63) wsum[wv] = x;
    __syncthreads();
    int woff = 0;
    for (int w = 0; w < wv; ++w) woff += wsum[w];
    int excl = woff + (x - s);
#pragma unroll
    for (int i = 0; i < 4; ++i) { int idx = base + i; if (idx < n1) rs[idx] = excl + v[i]; }
    if (t == 255) bsum[lb] = wsum[0] + wsum[1] + wsum[2] + wsum[3];
}

__global__ void scan1_3k(const int* c1, int* r1, int* b1, int n1a, int na,
                         const int* c2, int* r2, int* b2, int n1b, int nb,
                         const int* c3, int* r3, int* b3, int n1c, int nc,
                         int nbl1, int nbl2) {
    int b = blockIdx.x;
    if (b < nbl1)             scan1_body(c1, r1, b1, n1a, na, b);
    else if (b < nbl1 + nbl2) scan1_body(c2, r2, b2, n1b, nb, b - nbl1);
    else                      scan1_body(c3, r3, b3, n1c, nc, b - nbl1 - nbl2);
}

__device__ __forceinline__ void scan2_body(int* bsum, int nb, int* wsum) {
    int t = threadIdx.x;
    int s = (t < nb) ? bsum[t] : 0;
    int lane = t & 63, wv = t >> 6;
    int x = s;
#pragma unroll
    for (int off = 1; off < 64; off <<= 1) { int y = __shfl_up(x, off, 64); if (lane >= off) x += y; }
    if (lane == 63) wsum[wv] = x;
    __syncthreads();
    int woff = 0;
    for (int w = 0; w < wv; ++w) woff += wsum[w];
    if (t < nb) bsum[t] = woff + x - s;
    __syncthreads();
}

__global__ void scan2_3k(int* b1, int nb1, int* b2, int nb2, int* b3, int nb3) {
    __shared__ int wsum[4];
    scan2_body(b1, nb1, wsum);
    scan2_body(b2, nb2, wsum);
    scan2_body(b3, nb3, wsum);
}

// scan3 + cur-zeroing folded into one dispatch (trailing blocks zero cur arrays)
__global__ void scan3z_k(int* r1, const int* b1, int n1a,
                         int* r2, const int* b2, int n1b,
                         int* r3, const int* b3, int n1c, int nc1, int nc2, int nc3,
                         int* z1, int s1, int* z2, int s2, int* z3, int s3,
                         int nz1, int nz2) {
    int b = blockIdx.x;
    int scanb = nc1 + nc2 + nc3;
    if (b < scanb) {
        int* rs; const int* bsum; int n1; int lb;
        if (b < nc1)            { rs = r1; bsum = b1; n1 = n1a; lb = b; }
        else if (b < nc1 + nc2) { rs = r2; bsum = b2; n1 = n1b; lb = b - nc1; }
        else                    { rs = r3; bsum = b3; n1 = n1c; lb = b - nc1 - nc2; }
        int i = lb * 256 + threadIdx.x;
        if (i < n1) rs[i] += bsum[lb >> 2];
    } else {
        int zb = b - scanb;
        int* p; int n; int lb;
        if (zb < nz1)            { p = z1; n = s1; lb = zb; }
        else if (zb < nz1 + nz2) { p = z2; n = s2; lb = zb - nz1; }
        else                     { p = z3; n = s3; lb = zb - nz1 - nz2; }
        int i = lb * 256 + threadIdx.x;
        if (i < n) p[i] = 0;
    }
}

__global__ void fill3_k(const int* e1, int E1, const int* r1, int* c1, int* s1,
                        const int* e2, int E2, const int* r2, int* c2, int* s2,
                        const int* e3, int E3, const int* r3, int* c3, int* s3,
                        int nb1, int nb2) {
    int b = blockIdx.x;
    const int* edges; int E; const int* rs; int* cur; int* csrc; int lb;
    if (b < nb1)            { edges = e1; E = E1; rs = r1; cur = c1; csrc = s1; lb = b; }
    else if (b < nb1 + nb2) { edges = e2; E = E2; rs = r2; cur = c2; csrc = s2; lb = b - nb1; }
    else                    { edges = e3; E = E3; rs = r3; cur = c3; csrc = s3; lb = b - nb1 - nb2; }
    int e = lb * 256 + threadIdx.x;
    if (e >= E) return;
    int d = edges[E + e];
    int p = rs[d] + atomicAdd(&cur[d], 1);
    csrc[p] = edges[e];
}

// -------- layer-1 gather + relu (bf16 in/out), merged L3+L2.
struct NJob { const int* rs; const int* csrc; const bf162* m; const void* zin;
              void* zout; int R; int nb8; int nblocks; };

__device__ __forceinline__ void neigh_body(const NJob& jb, int blk, int t) {
    int b = (blk & 7) * jb.nb8 + (blk >> 3);
    int wv = t >> 6, lane = t & 63;
    int j = b * 8 + wv * 2 + (lane >> 5);
    int f2 = lane & 31;
    if (j >= jb.R) return;
    const bf162* m = jb.m;
    int s = jb.rs[j], e = jb.rs[j + 1];
    bf162 z0 = ((const bf162*)jb.zin)[(size_t)j * 32 + f2];
    float ax = bl(z0.x), ay = bl(z0.y);
    int k = s;
    for (; k + 8 <= e; k += 8) {
        int i0 = jb.csrc[k],     i1 = jb.csrc[k + 1], i2 = jb.csrc[k + 2], i3 = jb.csrc[k + 3];
        int i4 = jb.csrc[k + 4], i5 = jb.csrc[k + 5], i6 = jb.csrc[k + 6], i7 = jb.csrc[k + 7];
        bf162 v0 = m[(size_t)i0 * 32 + f2], v1 = m[(size_t)i1 * 32 + f2];
        bf162 v2 = m[(size_t)i2 * 32 + f2], v3 = m[(size_t)i3 * 32 + f2];
        bf162 v4 = m[(size_t)i4 * 32 + f2], v5 = m[(size_t)i5 * 32 + f2];
        bf162 v6 = m[(size_t)i6 * 32 + f2], v7 = m[(size_t)i7 * 32 + f2];
        ax += ((bl(v0.x) + bl(v1.x)) + (bl(v2.x) + bl(v3.x)))
            + ((bl(v4.x) + bl(v5.x)) + (bl(v6.x) + bl(v7.x)));
        ay += ((bl(v0.y) + bl(v1.y)) + (bl(v2.y) + bl(v3.y)))
            + ((bl(v4.y) + bl(v5.y)) + (bl(v6.y) + bl(v7.y)));
    }
    for (; k + 4 <= e; k += 4) {
        int i0 = jb.csrc[k], i1 = jb.csrc[k + 1], i2 = jb.csrc[k + 2], i3 = jb.csrc[k + 3];
        bf162 v0 = m[(size_t)i0 * 32 + f2], v1 = m[(size_t)i1 * 32 + f2];
        bf162 v2 = m[(size_t)i2 * 32 + f2], v3 = m[(size_t)i3 * 32 + f2];
        ax += (bl(v0.x) + bl(v1.x)) + (bl(v2.x) + bl(v3.x));
        ay += (bl(v0.y) + bl(v1.y)) + (bl(v2.y) + bl(v3.y));
    }
    for (; k < e; ++k) {
        bf162 v = m[(size_t)jb.csrc[k] * 32 + f2];
        ax += bl(v.x); ay += bl(v.y);
    }
    bf162 o; o.x = __float2bfloat16(fmaxf(ax, 0.f)); o.y = __float2bfloat16(fmaxf(ay, 0.f));
    ((bf162*)jb.zout)[(size_t)j * 32 + f2] = o;
}

__global__ void neighsum2_relu_k(NJob j3, NJob j2) {
    if ((int)blockIdx.x < j3.nblocks) neigh_body(j3, blockIdx.x, threadIdx.x);
    else                              neigh_body(j2, blockIdx.x - j3.nblocks, threadIdx.x);
}

// -------- merged layer-0 combined gather (bf162 interleaved tables)
__global__ void gatherZM23_k(
    const bf162* __restrict__ hAi, const bf162* __restrict__ hBi, const bf162* __restrict__ hCi,
    const int* __restrict__ ga, const int* __restrict__ gb, const int* __restrict__ gc,
    const float* __restrict__ iso3, const float* __restrict__ W13, const float* __restrict__ W23,
    bf16* __restrict__ zb3, bf16* __restrict__ m3, int n3, int jstep3, int nblk3,
    const bf162* __restrict__ hUi, const bf162* __restrict__ hVi,
    const int* __restrict__ gu, const int* __restrict__ gv,
    const float* __restrict__ iso2, const float* __restrict__ W12, const float* __restrict__ W22,
    bf16* __restrict__ zb2, bf16* __restrict__ m2, int n2, int jstep2) {
    int t = threadIdx.x;
    if ((int)blockIdx.x < nblk3) {
        int idx = blockIdx.x * 256 + t;
        int j = idx >> 6, f = idx & 63;
        float w1c[4], w2c[4];
#pragma unroll
        for (int c = 0; c < 4; ++c) {
            w1c[c] = W13[f * 196 + 192 + c];
            w2c[c] = W23[f * 196 + 192 + c];
        }
        const float4* I4 = (const float4*)iso3;
#pragma unroll
        for (int r = 0; r < 4; ++r, j += jstep3) {
            if (j >= n3) return;
            int a = ga[j], b = gb[j], c = gc[j];
            float4 iv = I4[j];
            bf162 va = hAi[(size_t)a * 64 + f];
            bf162 vb = hBi[(size_t)b * 64 + f];
            bf162 vc = hCi[(size_t)c * 64 + f];
            float zz = bl(va.x) + bl(vb.x) + bl(vc.x)
                     + iv.x * w1c[0] + iv.y * w1c[1] + iv.z * w1c[2] + iv.w * w1c[3];
            float mm = bl(va.y) + bl(vb.y) + bl(vc.y)
                     + iv.x * w2c[0] + iv.y * w2c[1] + iv.z * w2c[2] + iv.w * w2c[3];
            zb3[(size_t)j * HID + f] = __float2bfloat16(zz);
            m3[(size_t)j * HID + f] = __float2bfloat16(mm);
        }
    } else {
        int idx = (blockIdx.x - nblk3) * 256 + t;
        int j = idx >> 6, f = idx & 63;
        float w1c = W12[f * 129 + 128], w2c = W22[f * 129 + 128];
#pragma unroll
        for (int r = 0; r < 4; ++r, j += jstep2) {
            if (j >= n2) return;
            int u = gu[j], v = gv[j];
            float is = iso2[j];
            bf162 vu = hUi[(size_t)u * 64 + f];
            bf162 vv = hVi[(size_t)v * 64 + f];
            zb2[(size_t)j * HID + f] = __float2bfloat16(bl(vu.x) + bl(vv.x) + is * w1c);
            m2[(size_t)j * HID + f] = __float2bfloat16(bl(vu.y) + bl(vv.y) + is * w2c);
        }
    }
}

// -------- merged split segment sum (level 1 fp32, levels 2/3 bf16)
struct SJob { const void* h; int per; int coloff; int S; int nblocks; };

template <typename T>
__device__ __forceinline__ float ldconv(const T* p);
template <> __device__ __forceinline__ float ldconv<float>(const float* p) { return *p; }
template <> __device__ __forceinline__ float ldconv<bf16>(const bf16* p) { return bl(*p); }

template <typename T>
__device__ __forceinline__ void segsum_body(const SJob& jb, float* comb, int blk, int f) {
    int g = blk / jb.S, s = blk % jb.S;
    int r0 = s * 64;
    int r1 = min(jb.per, r0 + 64);
    float acc = 0.f;
    const T* p = (const T*)jb.h + ((size_t)g * jb.per + r0) * HID + f;
    for (int r = r0; r < r1; ++r) { acc += ldconv(p); p += HID; }
    atomicAdd(&comb[g * 192 + jb.coloff + f], acc);
}

__global__ void segsum3_k(SJob s1, SJob s2, SJob s3, float* comb) {
    int b = blockIdx.x, f = threadIdx.x;
    if (b < s1.nblocks)                    segsum_body<float>(s1, comb, b, f);
    else if (b < s1.nblocks + s2.nblocks)  segsum_body<bf16>(s2, comb, b - s1.nblocks, f);
    else                                   segsum_body<bf16>(s3, comb, b - s1.nblocks - s2.nblocks, f);
}

// -------- classifier
__global__ void classifier_k(const float* __restrict__ comb,
                             const float* __restrict__ cW1, const float* __restrict__ cb1,
                             const float* __restrict__ cW2, const float* __restrict__ cb2,
                             float* __restrict__ out) {
    __shared__ float row[192];
    __shared__ float hid[64];
    int g = blockIdx.x, t = threadIdx.x;
    for (int i = t; i < 192; i += 64) row[i] = comb[g * 192 + i];
    __syncthreads();
    float acc = cb1[t];
#pragma unroll 8
    for (int k = 0; k < 192; ++k) acc += row[k] * cW1[t * 192 + k];
    hid[t] = fmaxf(acc, 0.f);
    __syncthreads();
    if (t < 10) {
        float o = cb2[t];
#pragma unroll
        for (int k = 0; k < 64; ++k) o += hid[k] * cW2[t * 64 + k];
        out[g * 10 + t] = o;
    }
}

static inline int cdiv(long long a, long long b) { return (int)((a + b - 1) / b); }

extern "C" void kernel_launch(void* const* d_in, const int* in_sizes, int n_in,
                              void* d_out, int out_size, void* d_ws, size_t ws_size,
                              hipStream_t stream) {
    const float* x        = (const float*)d_in[0];
    const int*   eidx     = (const int*)d_in[1];
    const int*   gu2      = (const int*)d_in[3];
    const int*   gv2      = (const int*)d_in[4];
    const float* iso2     = (const float*)d_in[5];
    const int*   tedges   = (const int*)d_in[6];
    const int*   ga3      = (const int*)d_in[8];
    const int*   gb3      = (const int*)d_in[9];
    const int*   gc3      = (const int*)d_in[10];
    const float* iso3     = (const float*)d_in[11];
    const int*   hedges   = (const int*)d_in[12];
    const float* g1W1[3]  = {(const float*)d_in[14], (const float*)d_in[16], (const float*)d_in[18]};
    const float* g1W2[3]  = {(const float*)d_in[15], (const float*)d_in[17], (const float*)d_in[19]};
    const float* g2W1_0   = (const float*)d_in[20];
    const float* g2W2_0   = (const float*)d_in[21];
    const float* g2W1_1   = (const float*)d_in[22];
    const float* g2W2_1   = (const float*)d_in[23];
    const float* g3W1_0   = (const float*)d_in[24];
    const float* g3W2_0   = (const float*)d_in[25];
    const float* g3W1_1   = (const float*)d_in[26];
    const float* g3W2_1   = (const float*)d_in[27];
    const float* cW1      = (const float*)d_in[28];
    const float* cb1      = (const float*)d_in[29];
    const float* cW2      = (const float*)d_in[30];
    const float* cb2      = (const float*)d_in[31];
    float* out = (float*)d_out;

    const int N  = in_sizes[0] / 32;       // 2560
    const int E1 = in_sizes[1] / 2;
    const int n2 = in_sizes[3];            // 24320 (190*128)
    const int E2 = in_sizes[6] / 2;
    const int n3 = in_sizes[8];            // 145920 (1140*128)
    const int E3 = in_sizes[12] / 2;
    const int G  = out_size / 10;          // 128
    const int per1 = N / G, per2 = n2 / G, per3 = n3 / G;

    // ---- workspace carve-up
    float* ws = (float*)d_ws;
    size_t off = 0;
    auto alloc = [&](size_t n) { off = (off + 3) & ~(size_t)3; float* p = ws + off; off += n; return p; };
    const size_t NH = (size_t)N * HID;
    float* h0 = alloc(NH);
    bf162* hUi = (bf162*)alloc(NH); bf162* hVi = (bf162*)alloc(NH);
    bf162* hAi = (bf162*)alloc(NH); bf162* hBi = (bf162*)alloc(NH); bf162* hCi = (bf162*)alloc(NH);
    bf16* m2b = (bf16*)alloc((size_t)n2 * HID / 2 + 64);
    bf16* m2c = (bf16*)alloc((size_t)n2 * HID / 2 + 64);
    bf16* z2b = (bf16*)alloc((size_t)n2 * HID / 2 + 64);
    bf16* z2c = (bf16*)alloc((size_t)n2 * HID / 2 + 64);
    bf16* m3b = (bf16*)alloc((size_t)n3 * HID / 2 + 64);
    bf16* m3c = (bf16*)alloc((size_t)n3 * HID / 2 + 64);
    bf16* z3b = (bf16*)alloc((size_t)n3 * HID / 2 + 64);
    bf16* z3c = (bf16*)alloc((size_t)n3 * HID / 2 + 64);
    float* comb = alloc((size_t)G * 192);
    int* iws = (int*)(ws + off);
    size_t ioff = 0;
    auto ialloc = [&](size_t n) { int* p = iws + ioff; ioff += n; return p; };
    int* rs1 = ialloc(N + 1);  int* cur1 = ialloc(N);  int* csrc1 = ialloc(E1);
    int* rs2 = ialloc(n2 + 1); int* cur2 = ialloc(n2); int* csrc2 = ialloc(E2);
    int* rs3 = ialloc(n3 + 1); int* cur3 = ialloc(n3); int* csrc3 = ialloc(E3);
    int* bsum1 = ialloc(256); int* bsum2 = ialloc(256); int* bsum3 = ialloc(256);
    (void)ws_size;

    dim3 B256(256);
    auto mknjob = [&](const int* rs, const int* csrc, const bf16* m,
                      const void* zi, void* zo, int R) {
        NJob j; j.rs = rs; j.csrc = csrc; j.m = (const bf162*)m; j.zin = zi; j.zout = zo;
        j.R = R; int nb = cdiv(R, 8); j.nb8 = cdiv(nb, 8); j.nblocks = j.nb8 * 8; return j;
    };
    auto mkfjob = [&](const bf16* zb, const bf16* m, const int* rs, const int* csrc,
                      const float* Wa, const float* Wb, bf16* oa, bf16* ob, int R) {
        FJob j; j.zb = (const bf162*)zb; j.m = (const bf162*)m; j.rs = rs; j.csrc = csrc;
        j.Wa = Wa; j.Wb = Wb; j.oa = oa; j.ob = ob; j.R = R;
        j.nb8 = cdiv(cdiv(R, 128), 8); j.nblocks = j.nb8 * 8; return j;
    };

    // ---- batched CSR build (6 dispatches; cur re-zero folded into scan3z)
    int nz1 = cdiv(N, 256), nz2 = cdiv(n2, 256), nz3 = cdiv(n3, 256), nz4 = cdiv(G * 192, 256);
    zero4_k<<<nz1 + nz2 + nz3 + nz4, B256, 0, stream>>>(
        cur1, N, cur2, n2, cur3, n3, (int*)comb, G * 192, nz1, nz2, nz3);
    int ne1 = cdiv(E1, 256), ne2 = cdiv(E2, 256), ne3 = cdiv(E3, 256);
    hist3_k<<<ne1 + ne2 + ne3, B256, 0, stream>>>(
        eidx, E1, cur1, tedges, E2, cur2, hedges, E3, cur3, ne1, ne2);
    int ns1 = cdiv(N + 1, 1024), ns2 = cdiv(n2 + 1, 1024), ns3 = cdiv(n3 + 1, 1024);
    scan1_3k<<<ns1 + ns2 + ns3, B256, 0, stream>>>(
        cur1, rs1, bsum1, N + 1, N, cur2, rs2, bsum2, n2 + 1, n2,
        cur3, rs3, bsum3, n3 + 1, n3, ns1, ns2);
    scan2_3k<<<1, B256, 0, stream>>>(bsum1, ns1, bsum2, ns2, bsum3, ns3);
    int nc1 = cdiv(N + 1, 256), nc2 = cdiv(n2 + 1, 256), nc3 = cdiv(n3 + 1, 256);
    scan3z_k<<<nc1 + nc2 + nc3 + nz1 + nz2 + nz3, B256, 0, stream>>>(
        rs1, bsum1, N + 1, rs2, bsum2, n2 + 1, rs3, bsum3, n3 + 1, nc1, nc2, nc3,
        cur1, N, cur2, n2, cur3, n3, nz1, nz2);
    fill3_k<<<ne1 + ne2 + ne3, B256, 0, stream>>>(
        eidx, E1, rs1, cur1, csrc1, tedges, E2, rs2, cur2, csrc2,
        hedges, E3, rs3, cur3, csrc3, ne1, ne2);

    // ================= level 1: FUSED single kernel =================
    level1_k<<<G, B256, 0, stream>>>(x, rs1, csrc1,
        g1W1[0], g1W2[0], g1W1[1], g1W2[1], g1W1[2], g1W2[2], h0, per1);
    const float* h = h0;

    // ---- all 5 table GEMMs in ONE dispatch
    {
        TJobs5 jobs;
        jobs.j[0] = {g2W1_0, g2W2_0, hUi, 129, 0};
        jobs.j[1] = {g2W1_0, g2W2_0, hVi, 129, 64};
        jobs.j[2] = {g3W1_0, g3W2_0, hAi, 196, 0};
        jobs.j[3] = {g3W1_0, g3W2_0, hBi, 196, 64};
        jobs.j[4] = {g3W1_0, g3W2_0, hCi, 196, 128};
        int bpj = cdiv(cdiv(N, RPW), 4);
        gemm2_table<<<bpj * 5, B256, 0, stream>>>(h, jobs, N, bpj);
    }

    // ================= levels 2+3 merged =================
    {
        int jstep3 = cdiv(n3, 4), jstep2 = cdiv(n2, 4);
        int nblk3 = cdiv((long long)jstep3 * 64, 256);
        int nblk2 = cdiv((long long)jstep2 * 64, 256);
        gatherZM23_k<<<nblk3 + nblk2, B256, 0, stream>>>(
            hAi, hBi, hCi, ga3, gb3, gc3, iso3, g3W1_0, g3W2_0,
            z3b, m3b, n3, jstep3, nblk3,
            hUi, hVi, gu2, gv2, iso2, g2W1_0, g2W2_0, z2b, m2b, n2, jstep2);
    }
    // FUSED layer-0 neighsum + MFMA (reads zb/mb, writes zc + NEW messages mc)
    {
        FJob j3 = mkfjob(z3b, m3b, rs3, csrc3, g3W1_1, g3W2_1, z3c, m3c, n3);
        FJob j2 = mkfjob(z2b, m2b, rs2, csrc2, g2W1_1, g2W2_1, z2c, m2c, n2);
        neigh_mfma2_k<<<j3.nblocks + j2.nblocks, B256, 0, stream>>>(j3, j2);
    }
    // layer-1 neighbor sums (bf16, in-place on zc), merged
    {
        NJob j3 = mknjob(rs3, csrc3, m3c, z3c, z3c, n3);
        NJob j2 = mknjob(rs2, csrc2, m2c, z2c, z2c, n2);
        neighsum2_relu_k<<<j3.nblocks + j2.nblocks, B256, 0, stream>>>(j3, j2);
    }
    // all three segment sums, merged
    {
        SJob s1 = {h,   per1, 0,   cdiv(per1, 64), 0};
        SJob s2 = {z2c, per2, 64,  cdiv(per2, 64), 0};
        SJob s3 = {z3c, per3, 128, cdiv(per3, 64), 0};
        s1.nblocks = G * s1.S; s2.nblocks = G * s2.S; s3.nblocks = G * s3.S;
        segsum3_k<<<s1.nblocks + s2.nblocks + s3.nblocks, 64, 0, stream>>>(s1, s2, s3, comb);
    }

    // ================= classifier =================
    classifier_k<<<G, 64, 0, stream>>>(comb, cW1, cb1, cW2, cb2, out);
}

// Round 24
// 364.028 us; speedup vs baseline: 1.1417x; 1.1417x over previous
//
#include <hip/hip_runtime.h>
#include <hip/hip_bf16.h>

#define HID 64
#define RPW 16
#define KCH 8

typedef __hip_bfloat16  bf16;
typedef __hip_bfloat162 bf162;
typedef __attribute__((ext_vector_type(8))) short bf8v;
typedef __attribute__((ext_vector_type(4))) float f4v;
__device__ __forceinline__ float bl(bf16 h) { return __bfloat162float(h); }

// -------- FUSED level-1 GNN: one block per graph, 3 layers in LDS.
__global__ __launch_bounds__(256)
void level1_k(const float* __restrict__ x,
              const int* __restrict__ rs1, const int* __restrict__ csrc1,
              const float* __restrict__ W10, const float* __restrict__ W20,
              const float* __restrict__ W11, const float* __restrict__ W21,
              const float* __restrict__ W12, const float* __restrict__ W22,
              float* __restrict__ hout, int nper) {
    __shared__ float hbuf[20][64];
    __shared__ float mbuf[20][64];
    __shared__ float wl1[64 * 64];
    __shared__ float wl2[64 * 64];
    int g = blockIdx.x, t = threadIdx.x;
    int wv = t >> 6, lane = t & 63;
    int base = g * nper;
    for (int i = t; i < 20 * 32; i += 256)
        hbuf[i >> 5][i & 31] = x[(size_t)(base + (i >> 5)) * 32 + (i & 31)];
    const float* W1s[3] = {W10, W11, W12};
    const float* W2s[3] = {W20, W21, W22};
#pragma unroll 1
    for (int l = 0; l < 3; ++l) {
        int K = (l == 0) ? 32 : 64;
        const float* W1 = W1s[l];
        const float* W2 = W2s[l];
        __syncthreads();
        for (int i = t; i < K * 64; i += 256) {
            int k = i >> 6, col = i & 63;
            wl1[i] = W1[col * K + k];
            wl2[i] = W2[col * K + k];
        }
        __syncthreads();
        float accz[5], accm[5];
#pragma unroll
        for (int ri = 0; ri < 5; ++ri) {
            int r = wv + ri * 4;
            float az = 0.f, am = 0.f;
            for (int k = 0; k < K; ++k) {
                float hv = hbuf[r][k];
                az = fmaf(hv, wl1[k * 64 + lane], az);
                am = fmaf(hv, wl2[k * 64 + lane], am);
            }
            accz[ri] = az; accm[ri] = am;
        }
        __syncthreads();
#pragma unroll
        for (int ri = 0; ri < 5; ++ri)
            mbuf[wv + ri * 4][lane] = accm[ri];
        __syncthreads();
#pragma unroll
        for (int ri = 0; ri < 5; ++ri) {
            int r = wv + ri * 4;
            float acc = accz[ri];
            int s = rs1[base + r], e = rs1[base + r + 1];
            for (int k = s; k < e; ++k)
                acc += mbuf[csrc1[k] - base][lane];
            hbuf[r][lane] = fmaxf(acc, 0.f);
        }
    }
    __syncthreads();
    for (int i = t; i < 20 * 64; i += 256)
        hout[(size_t)(base + (i >> 6)) * 64 + (i & 63)] = hbuf[i >> 6][i & 63];
}

// -------- MFMA dual GEMM body (verified layouts m89/m120). Both outputs bf16.
// (R23 lesson: do NOT fuse the gather into this kernel — 16 serial row-gathers
// per thread at 1330-block TLP is latency-bound, 100us vs 369us total.)
struct MJob { const bf16* in; const float* Wa; const float* Wb; bf16* oa; bf16* ob; int R; int nblocks; };

__device__ __forceinline__ void mfma_body(const MJob& jb, int blk, int t) {
    __shared__ bf16 wl1[64][72];
    __shared__ bf16 wl2[64][72];
    {
        int n = t >> 2, k0 = (t & 3) * 16;
#pragma unroll
        for (int k = 0; k < 16; ++k) {
            wl1[n][k0 + k] = __float2bfloat16(jb.Wa[n * 64 + k0 + k]);
            wl2[n][k0 + k] = __float2bfloat16(jb.Wb[n * 64 + k0 + k]);
        }
    }
    __syncthreads();
    int lane = t & 63, wv = t >> 6;
    int quad = lane >> 4, m16 = lane & 15;
    int j0 = (blk * 4 + wv) * 32;
    if (j0 >= jb.R) return;
    bf8v a[2][2];
#pragma unroll
    for (int rt = 0; rt < 2; ++rt)
#pragma unroll
        for (int kt = 0; kt < 2; ++kt)
            a[rt][kt] = *(const bf8v*)(jb.in + (size_t)(j0 + rt * 16 + m16) * 64
                                             + kt * 32 + quad * 8);
#pragma unroll
    for (int n = 0; n < 4; ++n) {
        bf8v b1k0 = *(const bf8v*)&wl1[n * 16 + m16][quad * 8];
        bf8v b1k1 = *(const bf8v*)&wl1[n * 16 + m16][32 + quad * 8];
        bf8v b2k0 = *(const bf8v*)&wl2[n * 16 + m16][quad * 8];
        bf8v b2k1 = *(const bf8v*)&wl2[n * 16 + m16][32 + quad * 8];
#pragma unroll
        for (int rt = 0; rt < 2; ++rt) {
            f4v acca = {0.f, 0.f, 0.f, 0.f};
            f4v accb = {0.f, 0.f, 0.f, 0.f};
            acca = __builtin_amdgcn_mfma_f32_16x16x32_bf16(a[rt][0], b1k0, acca, 0, 0, 0);
            acca = __builtin_amdgcn_mfma_f32_16x16x32_bf16(a[rt][1], b1k1, acca, 0, 0, 0);
            accb = __builtin_amdgcn_mfma_f32_16x16x32_bf16(a[rt][0], b2k0, accb, 0, 0, 0);
            accb = __builtin_amdgcn_mfma_f32_16x16x32_bf16(a[rt][1], b2k1, accb, 0, 0, 0);
            int col = n * 16 + m16;
#pragma unroll
            for (int r = 0; r < 4; ++r) {
                int row = j0 + rt * 16 + quad * 4 + r;
                jb.oa[(size_t)row * 64 + col] = __float2bfloat16(acca[r]);
                jb.ob[(size_t)row * 64 + col] = __float2bfloat16(accb[r]);
            }
        }
    }
}

__global__ __launch_bounds__(256)
void gemm2_mfma2(MJob j3, MJob j2) {
    if ((int)blockIdx.x < j3.nblocks) mfma_body(j3, blockIdx.x, threadIdx.x);
    else                              mfma_body(j2, blockIdx.x - j3.nblocks, threadIdx.x);
}

// -------- batched table GEMM: 5 jobs, bf162 interleaved output.
struct TJob { const float* Wa; const float* Wb; bf162* o; int ldw; int coloff; };
struct TJobs5 { TJob j[5]; };

__global__ __attribute__((amdgpu_flat_work_group_size(256, 256),
                          amdgpu_waves_per_eu(6, 6)))
void gemm2_table(const float* in, TJobs5 jobs, int R, int bpj) {
    int jobi = blockIdx.x / bpj;
    int lb = blockIdx.x % bpj;
    TJob jb = jobs.j[jobi];
    int lane = threadIdx.x & 63;
    int wid = lb * 4 + (threadIdx.x >> 6);
    int j0 = __builtin_amdgcn_readfirstlane(wid * RPW);
    if (j0 >= R) return;
    float accx[RPW], accy[RPW];
#pragma unroll
    for (int r = 0; r < RPW; ++r) { accx[r] = 0.f; accy[r] = 0.f; }
    const float* pa = jb.Wa + (size_t)lane * jb.ldw + jb.coloff;
    const float* pb = jb.Wb + (size_t)lane * jb.ldw + jb.coloff;
#pragma unroll 1
    for (int kc = 0; kc < 64; kc += KCH) {
        float wx[KCH], wy[KCH];
#pragma unroll
        for (int kk = 0; kk < KCH; ++kk) { wx[kk] = pa[kc + kk]; wy[kk] = pb[kc + kk]; }
#pragma unroll
        for (int r = 0; r < RPW; ++r) {
            const float* rp = in + (size_t)(j0 + r) * 64 + kc;
#pragma unroll
            for (int kk = 0; kk < KCH; ++kk) {
                float s = rp[kk];
                accx[r] = fmaf(s, wx[kk], accx[r]);
                accy[r] = fmaf(s, wy[kk], accy[r]);
            }
        }
    }
#pragma unroll
    for (int r = 0; r < RPW; ++r) {
        int j = j0 + r;
        bf162 v; v.x = __float2bfloat16(accx[r]); v.y = __float2bfloat16(accy[r]);
        jb.o[(size_t)j * 64 + lane] = v;
    }
}

// ======== batched CSR build ========
__global__ void zero4_k(int* p1, int s1, int* p2, int s2, int* p3, int s3,
                        int* p4, int s4, int nb1, int nb2, int nb3) {
    int b = blockIdx.x; int* p; int n; int lb;
    if (b < nb1)                 { p = p1; n = s1; lb = b; }
    else if (b < nb1 + nb2)      { p = p2; n = s2; lb = b - nb1; }
    else if (b < nb1 + nb2 + nb3){ p = p3; n = s3; lb = b - nb1 - nb2; }
    else                         { p = p4; n = s4; lb = b - nb1 - nb2 - nb3; }
    int i = lb * 256 + threadIdx.x;
    if (i < n) p[i] = 0;
}

__global__ void hist3_k(const int* e1, int E1, int* c1,
                        const int* e2, int E2, int* c2,
                        const int* e3, int E3, int* c3, int nb1, int nb2) {
    int b = blockIdx.x; const int* dst; int* c; int E; int lb;
    if (b < nb1)            { dst = e1 + E1; c = c1; E = E1; lb = b; }
    else if (b < nb1 + nb2) { dst = e2 + E2; c = c2; E = E2; lb = b - nb1; }
    else                    { dst = e3 + E3; c = c3; E = E3; lb = b - nb1 - nb2; }
    int e = lb * 256 + threadIdx.x;
    if (e < E) atomicAdd(&c[dst[e]], 1);
}

__device__ __forceinline__ void scan1_body(const int* __restrict__ cnt, int* __restrict__ rs,
                                           int* __restrict__ bsum, int n1, int n, int lb) {
    __shared__ int wsum[4];
    int t = threadIdx.x;
    int base = lb * 1024 + t * 4;
    int v[4]; int s = 0;
#pragma unroll
    for (int i = 0; i < 4; ++i) { int idx = base + i; v[i] = s; s += (idx < n) ? cnt[idx] : 0; }
    int lane = t & 63, wv = t >> 6;
    int x = s;
#pragma unroll
    for (int off = 1; off < 64; off <<= 1) { int y = __shfl_up(x, off, 64); if (lane >= off) x += y; }
    if (lane == 63) wsum[wv] = x;
    __syncthreads();
    int woff = 0;
    for (int w = 0; w < wv; ++w) woff += wsum[w];
    int excl = woff + (x - s);
#pragma unroll
    for (int i = 0; i < 4; ++i) { int idx = base + i; if (idx < n1) rs[idx] = excl + v[i]; }
    if (t == 255) bsum[lb] = wsum[0] + wsum[1] + wsum[2] + wsum[3];
}

__global__ void scan1_3k(const int* c1, int* r1, int* b1, int n1a, int na,
                         const int* c2, int* r2, int* b2, int n1b, int nb,
                         const int* c3, int* r3, int* b3, int n1c, int nc,
                         int nbl1, int nbl2) {
    int b = blockIdx.x;
    if (b < nbl1)             scan1_body(c1, r1, b1, n1a, na, b);
    else if (b < nbl1 + nbl2) scan1_body(c2, r2, b2, n1b, nb, b - nbl1);
    else                      scan1_body(c3, r3, b3, n1c, nc, b - nbl1 - nbl2);
}

__device__ __forceinline__ void scan2_body(int* bsum, int nb, int* wsum) {
    int t = threadIdx.x;
    int s = (t < nb) ? bsum[t] : 0;
    int lane = t & 63, wv = t >> 6;
    int x = s;
#pragma unroll
    for (int off = 1; off < 64; off <<= 1) { int y = __shfl_up(x, off, 64); if (lane >= off) x += y; }
    if (lane == 63) wsum[wv] = x;
    __syncthreads();
    int woff = 0;
    for (int w = 0; w < wv; ++w) woff += wsum[w];
    if (t < nb) bsum[t] = woff + x - s;
    __syncthreads();
}

__global__ void scan2_3k(int* b1, int nb1, int* b2, int nb2, int* b3, int nb3) {
    __shared__ int wsum[4];
    scan2_body(b1, nb1, wsum);
    scan2_body(b2, nb2, wsum);
    scan2_body(b3, nb3, wsum);
}

// scan3 + cur-zeroing folded into one dispatch
__global__ void scan3z_k(int* r1, const int* b1, int n1a,
                         int* r2, const int* b2, int n1b,
                         int* r3, const int* b3, int n1c, int nc1, int nc2, int nc3,
                         int* z1, int s1, int* z2, int s2, int* z3, int s3,
                         int nz1, int nz2) {
    int b = blockIdx.x;
    int scanb = nc1 + nc2 + nc3;
    if (b < scanb) {
        int* rs; const int* bsum; int n1; int lb;
        if (b < nc1)            { rs = r1; bsum = b1; n1 = n1a; lb = b; }
        else if (b < nc1 + nc2) { rs = r2; bsum = b2; n1 = n1b; lb = b - nc1; }
        else                    { rs = r3; bsum = b3; n1 = n1c; lb = b - nc1 - nc2; }
        int i = lb * 256 + threadIdx.x;
        if (i < n1) rs[i] += bsum[lb >> 2];
    } else {
        int zb = b - scanb;
        int* p; int n; int lb;
        if (zb < nz1)            { p = z1; n = s1; lb = zb; }
        else if (zb < nz1 + nz2) { p = z2; n = s2; lb = zb - nz1; }
        else                     { p = z3; n = s3; lb = zb - nz1 - nz2; }
        int i = lb * 256 + threadIdx.x;
        if (i < n) p[i] = 0;
    }
}

__global__ void fill3_k(const int* e1, int E1, const int* r1, int* c1, int* s1,
                        const int* e2, int E2, const int* r2, int* c2, int* s2,
                        const int* e3, int E3, const int* r3, int* c3, int* s3,
                        int nb1, int nb2) {
    int b = blockIdx.x;
    const int* edges; int E; const int* rs; int* cur; int* csrc; int lb;
    if (b < nb1)            { edges = e1; E = E1; rs = r1; cur = c1; csrc = s1; lb = b; }
    else if (b < nb1 + nb2) { edges = e2; E = E2; rs = r2; cur = c2; csrc = s2; lb = b - nb1; }
    else                    { edges = e3; E = E3; rs = r3; cur = c3; csrc = s3; lb = b - nb1 - nb2; }
    int e = lb * 256 + threadIdx.x;
    if (e >= E) return;
    int d = edges[E + e];
    int p = rs[d] + atomicAdd(&cur[d], 1);
    csrc[p] = edges[e];
}

// -------- gather + relu (bf16 messages), bf16 in/out; merged L3+L2.
struct NJob { const int* rs; const int* csrc; const bf162* m; const void* zin;
              void* zout; int R; int nb8; int nblocks; };

__device__ __forceinline__ void neigh_body(const NJob& jb, int blk, int t) {
    int b = (blk & 7) * jb.nb8 + (blk >> 3);
    int wv = t >> 6, lane = t & 63;
    int j = b * 8 + wv * 2 + (lane >> 5);
    int f2 = lane & 31;
    if (j >= jb.R) return;
    const bf162* m = jb.m;
    int s = jb.rs[j], e = jb.rs[j + 1];
    bf162 z0 = ((const bf162*)jb.zin)[(size_t)j * 32 + f2];
    float ax = bl(z0.x), ay = bl(z0.y);
    int k = s;
    for (; k + 8 <= e; k += 8) {
        int i0 = jb.csrc[k],     i1 = jb.csrc[k + 1], i2 = jb.csrc[k + 2], i3 = jb.csrc[k + 3];
        int i4 = jb.csrc[k + 4], i5 = jb.csrc[k + 5], i6 = jb.csrc[k + 6], i7 = jb.csrc[k + 7];
        bf162 v0 = m[(size_t)i0 * 32 + f2], v1 = m[(size_t)i1 * 32 + f2];
        bf162 v2 = m[(size_t)i2 * 32 + f2], v3 = m[(size_t)i3 * 32 + f2];
        bf162 v4 = m[(size_t)i4 * 32 + f2], v5 = m[(size_t)i5 * 32 + f2];
        bf162 v6 = m[(size_t)i6 * 32 + f2], v7 = m[(size_t)i7 * 32 + f2];
        ax += ((bl(v0.x) + bl(v1.x)) + (bl(v2.x) + bl(v3.x)))
            + ((bl(v4.x) + bl(v5.x)) + (bl(v6.x) + bl(v7.x)));
        ay += ((bl(v0.y) + bl(v1.y)) + (bl(v2.y) + bl(v3.y)))
            + ((bl(v4.y) + bl(v5.y)) + (bl(v6.y) + bl(v7.y)));
    }
    for (; k + 4 <= e; k += 4) {
        int i0 = jb.csrc[k], i1 = jb.csrc[k + 1], i2 = jb.csrc[k + 2], i3 = jb.csrc[k + 3];
        bf162 v0 = m[(size_t)i0 * 32 + f2], v1 = m[(size_t)i1 * 32 + f2];
        bf162 v2 = m[(size_t)i2 * 32 + f2], v3 = m[(size_t)i3 * 32 + f2];
        ax += (bl(v0.x) + bl(v1.x)) + (bl(v2.x) + bl(v3.x));
        ay += (bl(v0.y) + bl(v1.y)) + (bl(v2.y) + bl(v3.y));
    }
    for (; k < e; ++k) {
        bf162 v = m[(size_t)jb.csrc[k] * 32 + f2];
        ax += bl(v.x); ay += bl(v.y);
    }
    bf162 o; o.x = __float2bfloat16(fmaxf(ax, 0.f)); o.y = __float2bfloat16(fmaxf(ay, 0.f));
    ((bf162*)jb.zout)[(size_t)j * 32 + f2] = o;
}

__global__ void neighsum2_relu_k(NJob j3, NJob j2) {
    if ((int)blockIdx.x < j3.nblocks) neigh_body(j3, blockIdx.x, threadIdx.x);
    else                              neigh_body(j2, blockIdx.x - j3.nblocks, threadIdx.x);
}

// -------- merged layer-0 combined gather (bf162 interleaved tables)
__global__ void gatherZM23_k(
    const bf162* __restrict__ hAi, const bf162* __restrict__ hBi, const bf162* __restrict__ hCi,
    const int* __restrict__ ga, const int* __restrict__ gb, const int* __restrict__ gc,
    const float* __restrict__ iso3, const float* __restrict__ W13, const float* __restrict__ W23,
    bf16* __restrict__ zb3, bf16* __restrict__ m3, int n3, int jstep3, int nblk3,
    const bf162* __restrict__ hUi, const bf162* __restrict__ hVi,
    const int* __restrict__ gu, const int* __restrict__ gv,
    const float* __restrict__ iso2, const float* __restrict__ W12, const float* __restrict__ W22,
    bf16* __restrict__ zb2, bf16* __restrict__ m2, int n2, int jstep2) {
    int t = threadIdx.x;
    if ((int)blockIdx.x < nblk3) {
        int idx = blockIdx.x * 256 + t;
        int j = idx >> 6, f = idx & 63;
        float w1c[4], w2c[4];
#pragma unroll
        for (int c = 0; c < 4; ++c) {
            w1c[c] = W13[f * 196 + 192 + c];
            w2c[c] = W23[f * 196 + 192 + c];
        }
        const float4* I4 = (const float4*)iso3;
#pragma unroll
        for (int r = 0; r < 4; ++r, j += jstep3) {
            if (j >= n3) return;
            int a = ga[j], b = gb[j], c = gc[j];
            float4 iv = I4[j];
            bf162 va = hAi[(size_t)a * 64 + f];
            bf162 vb = hBi[(size_t)b * 64 + f];
            bf162 vc = hCi[(size_t)c * 64 + f];
            float zz = bl(va.x) + bl(vb.x) + bl(vc.x)
                     + iv.x * w1c[0] + iv.y * w1c[1] + iv.z * w1c[2] + iv.w * w1c[3];
            float mm = bl(va.y) + bl(vb.y) + bl(vc.y)
                     + iv.x * w2c[0] + iv.y * w2c[1] + iv.z * w2c[2] + iv.w * w2c[3];
            zb3[(size_t)j * HID + f] = __float2bfloat16(zz);
            m3[(size_t)j * HID + f] = __float2bfloat16(mm);
        }
    } else {
        int idx = (blockIdx.x - nblk3) * 256 + t;
        int j = idx >> 6, f = idx & 63;
        float w1c = W12[f * 129 + 128], w2c = W22[f * 129 + 128];
#pragma unroll
        for (int r = 0; r < 4; ++r, j += jstep2) {
            if (j >= n2) return;
            int u = gu[j], v = gv[j];
            float is = iso2[j];
            bf162 vu = hUi[(size_t)u * 64 + f];
            bf162 vv = hVi[(size_t)v * 64 + f];
            zb2[(size_t)j * HID + f] = __float2bfloat16(bl(vu.x) + bl(vv.x) + is * w1c);
            m2[(size_t)j * HID + f] = __float2bfloat16(bl(vu.y) + bl(vv.y) + is * w2c);
        }
    }
}

// -------- merged split segment sum (level 1 fp32, levels 2/3 bf16)
struct SJob { const void* h; int per; int coloff; int S; int nblocks; };

template <typename T>
__device__ __forceinline__ float ldconv(const T* p);
template <> __device__ __forceinline__ float ldconv<float>(const float* p) { return *p; }
template <> __device__ __forceinline__ float ldconv<bf16>(const bf16* p) { return bl(*p); }

template <typename T>
__device__ __forceinline__ void segsum_body(const SJob& jb, float* comb, int blk, int f) {
    int g = blk / jb.S, s = blk % jb.S;
    int r0 = s * 64;
    int r1 = min(jb.per, r0 + 64);
    float acc = 0.f;
    const T* p = (const T*)jb.h + ((size_t)g * jb.per + r0) * HID + f;
    for (int r = r0; r < r1; ++r) { acc += ldconv(p); p += HID; }
    atomicAdd(&comb[g * 192 + jb.coloff + f], acc);
}

__global__ void segsum3_k(SJob s1, SJob s2, SJob s3, float* comb) {
    int b = blockIdx.x, f = threadIdx.x;
    if (b < s1.nblocks)                    segsum_body<float>(s1, comb, b, f);
    else if (b < s1.nblocks + s2.nblocks)  segsum_body<bf16>(s2, comb, b - s1.nblocks, f);
    else                                   segsum_body<bf16>(s3, comb, b - s1.nblocks - s2.nblocks, f);
}

// -------- classifier
__global__ void classifier_k(const float* __restrict__ comb,
                             const float* __restrict__ cW1, const float* __restrict__ cb1,
                             const float* __restrict__ cW2, const float* __restrict__ cb2,
                             float* __restrict__ out) {
    __shared__ float row[192];
    __shared__ float hid[64];
    int g = blockIdx.x, t = threadIdx.x;
    for (int i = t; i < 192; i += 64) row[i] = comb[g * 192 + i];
    __syncthreads();
    float acc = cb1[t];
#pragma unroll 8
    for (int k = 0; k < 192; ++k) acc += row[k] * cW1[t * 192 + k];
    hid[t] = fmaxf(acc, 0.f);
    __syncthreads();
    if (t < 10) {
        float o = cb2[t];
#pragma unroll
        for (int k = 0; k < 64; ++k) o += hid[k] * cW2[t * 64 + k];
        out[g * 10 + t] = o;
    }
}

static inline int cdiv(long long a, long long b) { return (int)((a + b - 1) / b); }

extern "C" void kernel_launch(void* const* d_in, const int* in_sizes, int n_in,
                              void* d_out, int out_size, void* d_ws, size_t ws_size,
                              hipStream_t stream) {
    const float* x        = (const float*)d_in[0];
    const int*   eidx     = (const int*)d_in[1];
    const int*   gu2      = (const int*)d_in[3];
    const int*   gv2      = (const int*)d_in[4];
    const float* iso2     = (const float*)d_in[5];
    const int*   tedges   = (const int*)d_in[6];
    const int*   ga3      = (const int*)d_in[8];
    const int*   gb3      = (const int*)d_in[9];
    const int*   gc3      = (const int*)d_in[10];
    const float* iso3     = (const float*)d_in[11];
    const int*   hedges   = (const int*)d_in[12];
    const float* g1W1[3]  = {(const float*)d_in[14], (const float*)d_in[16], (const float*)d_in[18]};
    const float* g1W2[3]  = {(const float*)d_in[15], (const float*)d_in[17], (const float*)d_in[19]};
    const float* g2W1_0   = (const float*)d_in[20];
    const float* g2W2_0   = (const float*)d_in[21];
    const float* g2W1_1   = (const float*)d_in[22];
    const float* g2W2_1   = (const float*)d_in[23];
    const float* g3W1_0   = (const float*)d_in[24];
    const float* g3W2_0   = (const float*)d_in[25];
    const float* g3W1_1   = (const float*)d_in[26];
    const float* g3W2_1   = (const float*)d_in[27];
    const float* cW1      = (const float*)d_in[28];
    const float* cb1      = (const float*)d_in[29];
    const float* cW2      = (const float*)d_in[30];
    const float* cb2      = (const float*)d_in[31];
    float* out = (float*)d_out;

    const int N  = in_sizes[0] / 32;       // 2560
    const int E1 = in_sizes[1] / 2;
    const int n2 = in_sizes[3];            // 24320
    const int E2 = in_sizes[6] / 2;
    const int n3 = in_sizes[8];            // 145920
    const int E3 = in_sizes[12] / 2;
    const int G  = out_size / 10;          // 128
    const int per1 = N / G, per2 = n2 / G, per3 = n3 / G;

    // ---- workspace carve-up
    float* ws = (float*)d_ws;
    size_t off = 0;
    auto alloc = [&](size_t n) { off = (off + 3) & ~(size_t)3; float* p = ws + off; off += n; return p; };
    const size_t NH = (size_t)N * HID;
    float* h0 = alloc(NH);
    bf162* hUi = (bf162*)alloc(NH); bf162* hVi = (bf162*)alloc(NH);
    bf162* hAi = (bf162*)alloc(NH); bf162* hBi = (bf162*)alloc(NH); bf162* hCi = (bf162*)alloc(NH);
    bf16* m2b = (bf16*)alloc((size_t)n2 * HID / 2 + 64);
    bf16* z2b = (bf16*)alloc((size_t)n2 * HID / 2 + 64);
    bf16* z2c = (bf16*)alloc((size_t)n2 * HID / 2 + 64);
    bf16* m3b = (bf16*)alloc((size_t)n3 * HID / 2 + 64);
    bf16* z3b = (bf16*)alloc((size_t)n3 * HID / 2 + 64);
    bf16* z3c = (bf16*)alloc((size_t)n3 * HID / 2 + 64);
    float* comb = alloc((size_t)G * 192);
    int* iws = (int*)(ws + off);
    size_t ioff = 0;
    auto ialloc = [&](size_t n) { int* p = iws + ioff; ioff += n; return p; };
    int* rs1 = ialloc(N + 1);  int* cur1 = ialloc(N);  int* csrc1 = ialloc(E1);
    int* rs2 = ialloc(n2 + 1); int* cur2 = ialloc(n2); int* csrc2 = ialloc(E2);
    int* rs3 = ialloc(n3 + 1); int* cur3 = ialloc(n3); int* csrc3 = ialloc(E3);
    int* bsum1 = ialloc(256); int* bsum2 = ialloc(256); int* bsum3 = ialloc(256);
    (void)ws_size;

    dim3 B256(256);
    auto mknjob = [&](const int* rs, const int* csrc, const bf16* m,
                      const void* zi, void* zo, int R) {
        NJob j; j.rs = rs; j.csrc = csrc; j.m = (const bf162*)m; j.zin = zi; j.zout = zo;
        j.R = R; int nb = cdiv(R, 8); j.nb8 = cdiv(nb, 8); j.nblocks = j.nb8 * 8; return j;
    };

    // ---- batched CSR build (6 dispatches; cur re-zero folded into scan3z)
    int nz1 = cdiv(N, 256), nz2 = cdiv(n2, 256), nz3 = cdiv(n3, 256), nz4 = cdiv(G * 192, 256);
    zero4_k<<<nz1 + nz2 + nz3 + nz4, B256, 0, stream>>>(
        cur1, N, cur2, n2, cur3, n3, (int*)comb, G * 192, nz1, nz2, nz3);
    int ne1 = cdiv(E1, 256), ne2 = cdiv(E2, 256), ne3 = cdiv(E3, 256);
    hist3_k<<<ne1 + ne2 + ne3, B256, 0, stream>>>(
        eidx, E1, cur1, tedges, E2, cur2, hedges, E3, cur3, ne1, ne2);
    int ns1 = cdiv(N + 1, 1024), ns2 = cdiv(n2 + 1, 1024), ns3 = cdiv(n3 + 1, 1024);
    scan1_3k<<<ns1 + ns2 + ns3, B256, 0, stream>>>(
        cur1, rs1, bsum1, N + 1, N, cur2, rs2, bsum2, n2 + 1, n2,
        cur3, rs3, bsum3, n3 + 1, n3, ns1, ns2);
    scan2_3k<<<1, B256, 0, stream>>>(bsum1, ns1, bsum2, ns2, bsum3, ns3);
    int nc1 = cdiv(N + 1, 256), nc2 = cdiv(n2 + 1, 256), nc3 = cdiv(n3 + 1, 256);
    scan3z_k<<<nc1 + nc2 + nc3 + nz1 + nz2 + nz3, B256, 0, stream>>>(
        rs1, bsum1, N + 1, rs2, bsum2, n2 + 1, rs3, bsum3, n3 + 1, nc1, nc2, nc3,
        cur1, N, cur2, n2, cur3, n3, nz1, nz2);
    fill3_k<<<ne1 + ne2 + ne3, B256, 0, stream>>>(
        eidx, E1, rs1, cur1, csrc1, tedges, E2, rs2, cur2, csrc2,
        hedges, E3, rs3, cur3, csrc3, ne1, ne2);

    // ================= level 1: FUSED single kernel =================
    level1_k<<<G, B256, 0, stream>>>(x, rs1, csrc1,
        g1W1[0], g1W2[0], g1W1[1], g1W2[1], g1W1[2], g1W2[2], h0, per1);
    const float* h = h0;

    // ---- all 5 table GEMMs in ONE dispatch
    {
        TJobs5 jobs;
        jobs.j[0] = {g2W1_0, g2W2_0, hUi, 129, 0};
        jobs.j[1] = {g2W1_0, g2W2_0, hVi, 129, 64};
        jobs.j[2] = {g3W1_0, g3W2_0, hAi, 196, 0};
        jobs.j[3] = {g3W1_0, g3W2_0, hBi, 196, 64};
        jobs.j[4] = {g3W1_0, g3W2_0, hCi, 196, 128};
        int bpj = cdiv(cdiv(N, RPW), 4);
        gemm2_table<<<bpj * 5, B256, 0, stream>>>(h, jobs, N, bpj);
    }

    // ================= levels 2+3 merged =================
    {
        int jstep3 = cdiv(n3, 4), jstep2 = cdiv(n2, 4);
        int nblk3 = cdiv((long long)jstep3 * 64, 256);
        int nblk2 = cdiv((long long)jstep2 * 64, 256);
        gatherZM23_k<<<nblk3 + nblk2, B256, 0, stream>>>(
            hAi, hBi, hCi, ga3, gb3, gc3, iso3, g3W1_0, g3W2_0,
            z3b, m3b, n3, jstep3, nblk3,
            hUi, hVi, gu2, gv2, iso2, g2W1_0, g2W2_0, z2b, m2b, n2, jstep2);
    }
    // layer-0 neighbor sums (bf16, in-place on zb), merged
    {
        NJob j3 = mknjob(rs3, csrc3, m3b, z3b, z3b, n3);
        NJob j2 = mknjob(rs2, csrc2, m2b, z2b, z2b, n2);
        neighsum2_relu_k<<<j3.nblocks + j2.nblocks, B256, 0, stream>>>(j3, j2);
    }
    // layer-1 MFMA dual GEMMs (both outputs bf16), merged
    {
        MJob j3 = {z3b, g3W1_1, g3W2_1, z3c, m3b, n3, cdiv(n3, 128)};
        MJob j2 = {z2b, g2W1_1, g2W2_1, z2c, m2b, n2, cdiv(n2, 128)};
        gemm2_mfma2<<<j3.nblocks + j2.nblocks, B256, 0, stream>>>(j3, j2);
    }
    // layer-1 neighbor sums (bf16, in-place on zc), merged
    {
        NJob j3 = mknjob(rs3, csrc3, m3b, z3c, z3c, n3);
        NJob j2 = mknjob(rs2, csrc2, m2b, z2c, z2c, n2);
        neighsum2_relu_k<<<j3.nblocks + j2.nblocks, B256, 0, stream>>>(j3, j2);
    }
    // all three segment sums, merged
    {
        SJob s1 = {h,   per1, 0,   cdiv(per1, 64), 0};
        SJob s2 = {z2c, per2, 64,  cdiv(per2, 64), 0};
        SJob s3 = {z3c, per3, 128, cdiv(per3, 64), 0};
        s1.nblocks = G * s1.S; s2.nblocks = G * s2.S; s3.nblocks = G * s3.S;
        segsum3_k<<<s1.nblocks + s2.nblocks + s3.nblocks, 64, 0, stream>>>(s1, s2, s3, comb);
    }

    // ================= classifier =================
    classifier_k<<<G, 64, 0, stream>>>(comb, cW1, cb1, cW2, cb2, out);
}